// Round 5
// baseline (189.140 us; speedup 1.0000x reference)
//
#include <hip/hip_runtime.h>

namespace {

constexpr int B  = 4;
constexpr int V  = 5000;
constexpr int NF = 10000;
constexpr int H  = 512;
constexpr int W  = 512;
constexpr int HW = H * W;          // 2^18
constexpr int NPIX = B * HW;

// output float offsets
constexpr int OFF_IMAGES  = 0;
constexpr int OFF_ALBEDO  = 3 * NPIX;
constexpr int OFF_ALPHA   = OFF_ALBEDO + 3 * NPIX;
constexpr int OFF_POSMASK = OFF_ALPHA + NPIX;
constexpr int OFF_SHADING = OFF_POSMASK + NPIX;
constexpr int OFF_GRID    = OFF_SHADING + 3 * NPIX;
constexpr int OFF_NORMALS = OFF_GRID + 2 * NPIX;

// SH constants
constexpr float C0 = 0.28209479177387814f;
constexpr float C1 = 1.0233267079464885f;
constexpr float C4 = 0.8580855308097834f;
constexpr float C7 = 0.42904276540489156f;
constexpr float C8 = 0.24770795610037571f;

// ---------------------------------------------------------------------------
// prep: single block builds CSR adjacency (count -> scan -> fill -> sort)
// key = phase*NF + f ; phase 0 = slot1, 1 = slot2, 2 = slot0 (reference order)
// ---------------------------------------------------------------------------
__global__ __launch_bounds__(1024) void prep_k(const int* __restrict__ faces,
                                               int* __restrict__ offsets,
                                               int* __restrict__ keys) {
    __shared__ int cnt[V];       // counts, then cursors
    __shared__ int part[1024];
    int t = threadIdx.x;
    for (int i = t; i < V; i += 1024) cnt[i] = 0;
    __syncthreads();
    for (int f = t; f < NF; f += 1024) {
        atomicAdd(&cnt[faces[f*3+0]], 1);
        atomicAdd(&cnt[faces[f*3+1]], 1);
        atomicAdd(&cnt[faces[f*3+2]], 1);
    }
    __syncthreads();
    // exclusive scan (chunked Hillis-Steele)
    constexpr int CH = (V + 1023) / 1024;   // 5
    int base_i = t * CH;
    int s = 0;
    int loc[CH];
#pragma unroll
    for (int j = 0; j < CH; ++j) {
        int i = base_i + j;
        loc[j] = (i < V) ? cnt[i] : 0;
        s += loc[j];
    }
    part[t] = s;
    __syncthreads();
    for (int d = 1; d < 1024; d <<= 1) {
        int v = (t >= d) ? part[t - d] : 0;
        __syncthreads();
        part[t] += v;
        __syncthreads();
    }
    int run = (t == 0) ? 0 : part[t - 1];
#pragma unroll
    for (int j = 0; j < CH; ++j) {
        int i = base_i + j;
        if (i < V) { cnt[i] = run; offsets[i] = run; run += loc[j]; }
    }
    if (t == 1023) offsets[V] = run;   // == total (last chunks are empty)
    __syncthreads();
    // fill (cursors in LDS; order scrambled, fixed by sort below)
    for (int f = t; f < NF; f += 1024) {
        int i0 = faces[f*3+0], i1 = faces[f*3+1], i2 = faces[f*3+2];
        int p;
        p = atomicAdd(&cnt[i1], 1); keys[p] = 0*NF + f;
        p = atomicAdd(&cnt[i2], 1); keys[p] = 1*NF + f;
        p = atomicAdd(&cnt[i0], 1); keys[p] = 2*NF + f;
    }
    __syncthreads();
    // per-vertex insertion sort (keys unique) -> deterministic reference order
    for (int v = t; v < V; v += 1024) {
        int lo = offsets[v], hi = offsets[v+1];
        for (int i = lo + 1; i < hi; ++i) {
            int k = keys[i];
            int j = i - 1;
            while (j >= lo && keys[j] > k) { keys[j+1] = keys[j]; --j; }
            keys[j+1] = k;
        }
    }
}

// per (b,v): accumulate face normals in exact reference order, normalize, write
__global__ void accum_k(const int* __restrict__ offsets, const int* __restrict__ keys,
                        const int* __restrict__ faces,
                        const float* __restrict__ verts, const float* __restrict__ tverts,
                        float* __restrict__ normV, float* __restrict__ normT) {
    int i = blockIdx.x * blockDim.x + threadIdx.x;
    if (i >= B * V) return;
    int b = i / V, v = i - b * V;
    const float* vb = verts  + (size_t)b * V * 3;
    const float* tb = tverts + (size_t)b * V * 3;
    float nx = 0, ny = 0, nz = 0, tx = 0, ty = 0, tz = 0;
    int lo = offsets[v], hi = offsets[v+1];
    for (int e = lo; e < hi; ++e) {
        int key = keys[e];
        int phase = key / NF;
        int f = key - phase * NF;
        int j0 = faces[f*3+0], j1 = faces[f*3+1], j2 = faces[f*3+2];
        {
            float x0 = vb[j0*3], y0 = vb[j0*3+1], z0 = vb[j0*3+2];
            float x1 = vb[j1*3], y1 = vb[j1*3+1], z1 = vb[j1*3+2];
            float x2 = vb[j2*3], y2 = vb[j2*3+1], z2 = vb[j2*3+2];
            float ax, ay, az, bx, by, bz;
            if (phase == 0)      { ax=x2-x1; ay=y2-y1; az=z2-z1; bx=x0-x1; by=y0-y1; bz=z0-z1; }
            else if (phase == 1) { ax=x0-x2; ay=y0-y2; az=z0-z2; bx=x1-x2; by=y1-y2; bz=z1-z2; }
            else                 { ax=x1-x0; ay=y1-y0; az=z1-z0; bx=x2-x0; by=y2-y0; bz=z2-z0; }
            nx += ay*bz - az*by;
            ny += az*bx - ax*bz;
            nz += ax*by - ay*bx;
        }
        {
            float x0 = tb[j0*3], y0 = tb[j0*3+1], z0 = tb[j0*3+2] + 10.0f;
            float x1 = tb[j1*3], y1 = tb[j1*3+1], z1 = tb[j1*3+2] + 10.0f;
            float x2 = tb[j2*3], y2 = tb[j2*3+1], z2 = tb[j2*3+2] + 10.0f;
            float ax, ay, az, bx, by, bz;
            if (phase == 0)      { ax=x2-x1; ay=y2-y1; az=z2-z1; bx=x0-x1; by=y0-y1; bz=z0-z1; }
            else if (phase == 1) { ax=x0-x2; ay=y0-y2; az=z0-z2; bx=x1-x2; by=y1-y2; bz=z1-z2; }
            else                 { ax=x1-x0; ay=y1-y0; az=z1-z0; bx=x2-x0; by=y2-y0; bz=z2-z0; }
            tx += ay*bz - az*by;
            ty += az*bx - ax*bz;
            tz += ax*by - ay*bx;
        }
    }
    {
        float inv = 1.0f / fmaxf(sqrtf(nx*nx + ny*ny + nz*nz), 1e-6f);
        normV[i*3+0] = nx*inv; normV[i*3+1] = ny*inv; normV[i*3+2] = nz*inv;
    }
    {
        float inv = 1.0f / fmaxf(sqrtf(tx*tx + ty*ty + tz*tz), 1e-6f);
        normT[i*3+0] = tx*inv; normT[i*3+1] = ty*inv; normT[i*3+2] = tz*inv;
    }
}

// fused pack: [0,NPIX) -> albedo RGBX ; [NPIX, NPIX+B*NF) -> slim face table
// face row (6 float4, 96B stride, only 0..4 used):
//  q0=(u0,v0,tz0,n0x) q1=(n0y,n0z,u1,v1) q2=(tz1,n1x,n1y,n1z)
//  q3=(u2,v2,tz2,n2x) q4=(n2y,n2z,0,0)
__global__ __launch_bounds__(256) void pack_k(const int* __restrict__ faces,
                                              const float* __restrict__ fuv,
                                              const float* __restrict__ normV,
                                              const float* __restrict__ normT,
                                              const float* __restrict__ albedo,
                                              float4* __restrict__ ftab,
                                              float4* __restrict__ apack) {
    int gid = blockIdx.x * 256 + threadIdx.x;
    if (gid < NPIX) {
        int b = gid >> 18, hw = gid & (HW - 1);
        const float* ab = albedo + (size_t)b * 3 * HW;
        apack[gid] = make_float4(ab[hw], ab[HW + hw], ab[2*HW + hw], 0.0f);
    } else {
        int i = gid - NPIX;
        if (i >= B * NF) return;
        int b = i / NF, fi = i - b * NF;
        int v0 = faces[fi*3+0], v1 = faces[fi*3+1], v2 = faces[fi*3+2];
        const float* uv = fuv + (size_t)fi * 9;
        int g0 = (b*V + v0)*3, g1 = (b*V + v1)*3, g2 = (b*V + v2)*3;
        float4* row = ftab + (size_t)i * 6;
        row[0] = make_float4(uv[0], uv[1], normT[g0+2], normV[g0+0]);
        row[1] = make_float4(normV[g0+1], normV[g0+2], uv[3], uv[4]);
        row[2] = make_float4(normT[g1+2], normV[g1+0], normV[g1+1], normV[g1+2]);
        row[3] = make_float4(uv[6], uv[7], normT[g2+2], normV[g2+0]);
        row[4] = make_float4(normV[g2+1], normV[g2+2], 0.0f, 0.0f);
    }
}

__global__ __launch_bounds__(256) void pixel_k(
    const int*    __restrict__ ptf,
    const float*  __restrict__ bary,
    const float4* __restrict__ apack,
    const float*  __restrict__ lights,
    const float4* __restrict__ ftab,
    float*        __restrict__ out) {
    int pix = blockIdx.x * 256 + threadIdx.x;
    int b  = pix >> 18;
    int hw = pix & (HW - 1);

    int f = ptf[pix];
    float vis = (f >= 0) ? 1.0f : 0.0f;
    int fs = (f >= 0) ? f : 0;
    float w0 = bary[pix*3+0] * vis;
    float w1 = bary[pix*3+1] * vis;
    float w2 = bary[pix*3+2] * vis;

    const float4* fr = ftab + (size_t)fs * 6;
    float4 q0 = fr[0], q1 = fr[1], q2 = fr[2], q3 = fr[3], q4 = fr[4];
    // per-channel accumulation order identical to the k=0,1,2 += chain
    float u  = w0*q0.x + w1*q1.z + w2*q3.x;
    float v  = w0*q0.y + w1*q1.w + w2*q3.y;
    float tz = w0*q0.z + w1*q2.x + w2*q3.z;
    float nx = w0*q0.w + w1*q2.y + w2*q3.w;
    float ny = w0*q1.x + w1*q2.z + w2*q4.x;
    float nz = w0*q1.y + w1*q2.w + w2*q4.y;

    // SH shading (all pixels; n=0 for masked)
    float shb[9] = {C0, C1*nx, C1*ny, C1*nz, C4*nx*ny, C4*nx*nz, C4*ny*nz,
                    C7*(nx*nx - ny*ny), C8*(3.0f*nz*nz - 1.0f)};
    const float* L = lights + (size_t)__builtin_amdgcn_readfirstlane(b) * 27;
    float s0 = 0.0f, s1 = 0.0f, s2 = 0.0f;
#pragma unroll
    for (int k = 0; k < 9; ++k) {
        float sk = shb[k];
        s0 += L[k*3+0]*sk; s1 += L[k*3+1]*sk; s2 += L[k*3+2]*sk;
    }

    // bilinear albedo at grid=(u,v) (all pixels, incl. masked -> (0,0))
    float gx = (u + 1.0f) * 0.5f * (float)W - 0.5f;
    float gy = (v + 1.0f) * 0.5f * (float)H - 0.5f;
    float x0 = floorf(gx), y0 = floorf(gy);
    float wx1 = gx - x0, wx0 = 1.0f - wx1;
    float wy1 = gy - y0, wy0 = 1.0f - wy1;
    float a0 = 0.0f, a1 = 0.0f, a2 = 0.0f;
    {
        float fx[4] = {x0, x0 + 1.0f, x0,        x0 + 1.0f};
        float fy[4] = {y0, y0,        y0 + 1.0f, y0 + 1.0f};
        float wt[4] = {wx0*wy0, wx1*wy0, wx0*wy1, wx1*wy1};
#pragma unroll
        for (int c = 0; c < 4; ++c) {
            bool valid = (fx[c] >= 0.0f) && (fx[c] <= (float)(W-1)) &&
                         (fy[c] >= 0.0f) && (fy[c] <= (float)(H-1));
            if (valid) {
                int ix = (int)fx[c];
                int iy = (int)fy[c];
                float4 t = apack[(b << 18) + iy * W + ix];
                float wgt = wt[c];
                a0 += wgt * t.x; a1 += wgt * t.y; a2 += wgt * t.z;
            }
        }
    }

    int obase = b * 3 * HW + hw;
    out[OFF_IMAGES + obase         ] = a0 * s0 * vis;
    out[OFF_IMAGES + obase +   HW  ] = a1 * s1 * vis;
    out[OFF_IMAGES + obase + 2*HW  ] = a2 * s2 * vis;
    out[OFF_ALBEDO + obase         ] = a0;
    out[OFF_ALBEDO + obase +   HW  ] = a1;
    out[OFF_ALBEDO + obase + 2*HW  ] = a2;
    out[OFF_ALPHA   + pix] = vis;
    out[OFF_POSMASK + pix] = (tz < -0.05f) ? 1.0f : 0.0f;
    out[OFF_SHADING + obase        ] = s0;
    out[OFF_SHADING + obase +   HW ] = s1;
    out[OFF_SHADING + obase + 2*HW ] = s2;
    *reinterpret_cast<float2*>(out + OFF_GRID + (size_t)pix*2) = make_float2(u, v);
}

} // namespace

extern "C" void kernel_launch(void* const* d_in, const int* in_sizes, int n_in,
                              void* d_out, int out_size, void* d_ws, size_t ws_size,
                              hipStream_t stream) {
    const float* verts  = (const float*)d_in[0];
    const float* tverts = (const float*)d_in[1];
    const float* albedo = (const float*)d_in[2];
    const float* lights = (const float*)d_in[3];
    const float* fuv    = (const float*)d_in[4];
    const float* bary   = (const float*)d_in[5];
    const int*   faces  = (const int*)d_in[6];
    const int*   ptf    = (const int*)d_in[7];
    float* out = (float*)d_out;

    char* ws = (char*)d_ws;
    int* offsets = (int*)ws;                              // V+1
    int* keys    = offsets + V + 1;                       // 3*NF
    float* normT = (float*)(keys + 3*NF);                 // B*V*3
    char* pend   = (char*)(normT + (size_t)B*V*3);
    size_t ftab_off  = (((size_t)(pend - ws)) + 255) & ~(size_t)255;
    size_t apack_off = (ftab_off + (size_t)B*NF*6*sizeof(float4) + 255) & ~(size_t)255;
    float4* ftab  = (float4*)(ws + ftab_off);             // 3.84 MB
    float4* apack = (float4*)(ws + apack_off);            // 16.78 MB
    float* normV = out + OFF_NORMALS;

    prep_k<<<1, 1024, 0, stream>>>(faces, offsets, keys);
    accum_k<<<(B*V + 255)/256, 256, 0, stream>>>(offsets, keys, faces, verts, tverts,
                                                 normV, normT);
    int pack_blocks = NPIX/256 + (B*NF + 255)/256;
    pack_k<<<pack_blocks, 256, 0, stream>>>(faces, fuv, normV, normT, albedo, ftab, apack);
    pixel_k<<<NPIX/256, 256, 0, stream>>>(ptf, bary, apack, lights, ftab, out);
}

// Round 6
// 113.916 us; speedup vs baseline: 1.6604x; 1.6604x over previous
//
#include <hip/hip_runtime.h>

namespace {

constexpr int B  = 4;
constexpr int V  = 5000;
constexpr int NF = 10000;
constexpr int H  = 512;
constexpr int W  = 512;
constexpr int HW = H * W;          // 2^18
constexpr int NPIX = B * HW;

// output float offsets
constexpr int OFF_IMAGES  = 0;
constexpr int OFF_ALBEDO  = 3 * NPIX;
constexpr int OFF_ALPHA   = OFF_ALBEDO + 3 * NPIX;
constexpr int OFF_POSMASK = OFF_ALPHA + NPIX;
constexpr int OFF_SHADING = OFF_POSMASK + NPIX;
constexpr int OFF_GRID    = OFF_SHADING + 3 * NPIX;
constexpr int OFF_NORMALS = OFF_GRID + 2 * NPIX;

// SH constants
constexpr float C0 = 0.28209479177387814f;
constexpr float C1 = 1.0233267079464885f;
constexpr float C4 = 0.8580855308097834f;
constexpr float C7 = 0.42904276540489156f;
constexpr float C8 = 0.24770795610037571f;

// ---- CSR adjacency build (multi-block; deterministic after sort_k) --------
// key = phase*NF + f ; phase 0 = slot1, 1 = slot2, 2 = slot0 (reference order)

__global__ void count_k(const int* __restrict__ faces, int* __restrict__ counts) {
    int f = blockIdx.x * blockDim.x + threadIdx.x;
    if (f >= NF) return;
    atomicAdd(&counts[faces[f*3+0]], 1);
    atomicAdd(&counts[faces[f*3+1]], 1);
    atomicAdd(&counts[faces[f*3+2]], 1);
}

__global__ __launch_bounds__(1024) void scan_k(const int* __restrict__ counts,
                                               int* __restrict__ offsets,
                                               int* __restrict__ cursor) {
    __shared__ int part[1024];
    constexpr int CH = (V + 1023) / 1024;   // 5
    int t = threadIdx.x;
    int i0 = t * CH;
    int loc[CH];
    int s = 0;
#pragma unroll
    for (int j = 0; j < CH; ++j) {
        int i = i0 + j;
        loc[j] = (i < V) ? counts[i] : 0;
        s += loc[j];
    }
    part[t] = s;
    __syncthreads();
    for (int d = 1; d < 1024; d <<= 1) {
        int v = (t >= d) ? part[t - d] : 0;
        __syncthreads();
        part[t] += v;
        __syncthreads();
    }
    int run = (t == 0) ? 0 : part[t - 1];
#pragma unroll
    for (int j = 0; j < CH; ++j) {
        int i = i0 + j;
        if (i < V) { offsets[i] = run; cursor[i] = run; run += loc[j]; }
    }
    if (t == 1023) offsets[V] = run;
}

__global__ void fill_k(const int* __restrict__ faces, int* __restrict__ cursor,
                       int* __restrict__ keys) {
    int f = blockIdx.x * blockDim.x + threadIdx.x;
    if (f >= NF) return;
    int i0 = faces[f*3+0], i1 = faces[f*3+1], i2 = faces[f*3+2];
    int p;
    p = atomicAdd(&cursor[i1], 1); keys[p] = 0*NF + f;
    p = atomicAdd(&cursor[i2], 1); keys[p] = 1*NF + f;
    p = atomicAdd(&cursor[i0], 1); keys[p] = 2*NF + f;
}

// per-vertex insertion sort (keys unique) -> deterministic reference order
__global__ void sort_k(const int* __restrict__ offsets, int* __restrict__ keys) {
    int v = blockIdx.x * blockDim.x + threadIdx.x;
    if (v >= V) return;
    int lo = offsets[v], hi = offsets[v+1];
    for (int i = lo + 1; i < hi; ++i) {
        int k = keys[i];
        int j = i - 1;
        while (j >= lo && keys[j] > k) { keys[j+1] = keys[j]; --j; }
        keys[j+1] = k;
    }
}

// per (b,v): accumulate face normals in exact reference order, normalize, write
__global__ void accum_k(const int* __restrict__ offsets, const int* __restrict__ keys,
                        const int* __restrict__ faces,
                        const float* __restrict__ verts, const float* __restrict__ tverts,
                        float* __restrict__ normV, float* __restrict__ normT) {
    int i = blockIdx.x * blockDim.x + threadIdx.x;
    if (i >= B * V) return;
    int b = i / V, v = i - b * V;
    const float* vb = verts  + (size_t)b * V * 3;
    const float* tb = tverts + (size_t)b * V * 3;
    float nx = 0, ny = 0, nz = 0, tx = 0, ty = 0, tz = 0;
    int lo = offsets[v], hi = offsets[v+1];
    for (int e = lo; e < hi; ++e) {
        int key = keys[e];
        int phase = key / NF;
        int f = key - phase * NF;
        int j0 = faces[f*3+0], j1 = faces[f*3+1], j2 = faces[f*3+2];
        {
            float x0 = vb[j0*3], y0 = vb[j0*3+1], z0 = vb[j0*3+2];
            float x1 = vb[j1*3], y1 = vb[j1*3+1], z1 = vb[j1*3+2];
            float x2 = vb[j2*3], y2 = vb[j2*3+1], z2 = vb[j2*3+2];
            float ax, ay, az, bx, by, bz;
            if (phase == 0)      { ax=x2-x1; ay=y2-y1; az=z2-z1; bx=x0-x1; by=y0-y1; bz=z0-z1; }
            else if (phase == 1) { ax=x0-x2; ay=y0-y2; az=z0-z2; bx=x1-x2; by=y1-y2; bz=z1-z2; }
            else                 { ax=x1-x0; ay=y1-y0; az=z1-z0; bx=x2-x0; by=y2-y0; bz=z2-z0; }
            nx += ay*bz - az*by;
            ny += az*bx - ax*bz;
            nz += ax*by - ay*bx;
        }
        {
            float x0 = tb[j0*3], y0 = tb[j0*3+1], z0 = tb[j0*3+2] + 10.0f;
            float x1 = tb[j1*3], y1 = tb[j1*3+1], z1 = tb[j1*3+2] + 10.0f;
            float x2 = tb[j2*3], y2 = tb[j2*3+1], z2 = tb[j2*3+2] + 10.0f;
            float ax, ay, az, bx, by, bz;
            if (phase == 0)      { ax=x2-x1; ay=y2-y1; az=z2-z1; bx=x0-x1; by=y0-y1; bz=z0-z1; }
            else if (phase == 1) { ax=x0-x2; ay=y0-y2; az=z0-z2; bx=x1-x2; by=y1-y2; bz=z1-z2; }
            else                 { ax=x1-x0; ay=y1-y0; az=z1-z0; bx=x2-x0; by=y2-y0; bz=z2-z0; }
            tx += ay*bz - az*by;
            ty += az*bx - ax*bz;
            tz += ax*by - ay*bx;
        }
    }
    {
        float inv = 1.0f / fmaxf(sqrtf(nx*nx + ny*ny + nz*nz), 1e-6f);
        normV[i*3+0] = nx*inv; normV[i*3+1] = ny*inv; normV[i*3+2] = nz*inv;
    }
    {
        float inv = 1.0f / fmaxf(sqrtf(tx*tx + ty*ty + tz*tz), 1e-6f);
        normT[i*3+0] = tx*inv; normT[i*3+1] = ty*inv; normT[i*3+2] = tz*inv;
    }
}

// fused pack: [0,NPIX) -> albedo RGBX ; [NPIX, NPIX+B*NF) -> slim face table
// face row (6 float4, 96B stride, only 0..4 used):
//  q0=(u0,v0,tz0,n0x) q1=(n0y,n0z,u1,v1) q2=(tz1,n1x,n1y,n1z)
//  q3=(u2,v2,tz2,n2x) q4=(n2y,n2z,0,0)
__global__ __launch_bounds__(256) void pack_k(const int* __restrict__ faces,
                                              const float* __restrict__ fuv,
                                              const float* __restrict__ normV,
                                              const float* __restrict__ normT,
                                              const float* __restrict__ albedo,
                                              float4* __restrict__ ftab,
                                              float4* __restrict__ apack) {
    int gid = blockIdx.x * 256 + threadIdx.x;
    if (gid < NPIX) {
        int b = gid >> 18, hw = gid & (HW - 1);
        const float* ab = albedo + (size_t)b * 3 * HW;
        apack[gid] = make_float4(ab[hw], ab[HW + hw], ab[2*HW + hw], 0.0f);
    } else {
        int i = gid - NPIX;
        if (i >= B * NF) return;
        int b = i / NF, fi = i - b * NF;
        int v0 = faces[fi*3+0], v1 = faces[fi*3+1], v2 = faces[fi*3+2];
        const float* uv = fuv + (size_t)fi * 9;
        int g0 = (b*V + v0)*3, g1 = (b*V + v1)*3, g2 = (b*V + v2)*3;
        float4* row = ftab + (size_t)i * 6;
        row[0] = make_float4(uv[0], uv[1], normT[g0+2], normV[g0+0]);
        row[1] = make_float4(normV[g0+1], normV[g0+2], uv[3], uv[4]);
        row[2] = make_float4(normT[g1+2], normV[g1+0], normV[g1+1], normV[g1+2]);
        row[3] = make_float4(uv[6], uv[7], normT[g2+2], normV[g2+0]);
        row[4] = make_float4(normV[g2+1], normV[g2+2], 0.0f, 0.0f);
    }
}

__global__ __launch_bounds__(256) void pixel_k(
    const int*    __restrict__ ptf,
    const float*  __restrict__ bary,
    const float4* __restrict__ apack,
    const float*  __restrict__ lights,
    const float4* __restrict__ ftab,
    float*        __restrict__ out) {
    int pix = blockIdx.x * 256 + threadIdx.x;
    int b  = pix >> 18;
    int hw = pix & (HW - 1);

    int f = ptf[pix];
    float vis = (f >= 0) ? 1.0f : 0.0f;
    int fs = (f >= 0) ? f : 0;
    float w0 = bary[pix*3+0] * vis;
    float w1 = bary[pix*3+1] * vis;
    float w2 = bary[pix*3+2] * vis;

    const float4* fr = ftab + (size_t)fs * 6;
    float4 q0 = fr[0], q1 = fr[1], q2 = fr[2], q3 = fr[3], q4 = fr[4];
    // per-channel accumulation order identical to the k=0,1,2 += chain
    float u  = w0*q0.x + w1*q1.z + w2*q3.x;
    float v  = w0*q0.y + w1*q1.w + w2*q3.y;
    float tz = w0*q0.z + w1*q2.x + w2*q3.z;
    float nx = w0*q0.w + w1*q2.y + w2*q3.w;
    float ny = w0*q1.x + w1*q2.z + w2*q4.x;
    float nz = w0*q1.y + w1*q2.w + w2*q4.y;

    // SH shading (all pixels; n=0 for masked)
    float shb[9] = {C0, C1*nx, C1*ny, C1*nz, C4*nx*ny, C4*nx*nz, C4*ny*nz,
                    C7*(nx*nx - ny*ny), C8*(3.0f*nz*nz - 1.0f)};
    const float* L = lights + (size_t)__builtin_amdgcn_readfirstlane(b) * 27;
    float s0 = 0.0f, s1 = 0.0f, s2 = 0.0f;
#pragma unroll
    for (int k = 0; k < 9; ++k) {
        float sk = shb[k];
        s0 += L[k*3+0]*sk; s1 += L[k*3+1]*sk; s2 += L[k*3+2]*sk;
    }

    // bilinear albedo at grid=(u,v) (all pixels, incl. masked -> (0,0))
    float gx = (u + 1.0f) * 0.5f * (float)W - 0.5f;
    float gy = (v + 1.0f) * 0.5f * (float)H - 0.5f;
    float x0 = floorf(gx), y0 = floorf(gy);
    float wx1 = gx - x0, wx0 = 1.0f - wx1;
    float wy1 = gy - y0, wy0 = 1.0f - wy1;
    float a0 = 0.0f, a1 = 0.0f, a2 = 0.0f;
    {
        float fx[4] = {x0, x0 + 1.0f, x0,        x0 + 1.0f};
        float fy[4] = {y0, y0,        y0 + 1.0f, y0 + 1.0f};
        float wt[4] = {wx0*wy0, wx1*wy0, wx0*wy1, wx1*wy1};
#pragma unroll
        for (int c = 0; c < 4; ++c) {
            bool valid = (fx[c] >= 0.0f) && (fx[c] <= (float)(W-1)) &&
                         (fy[c] >= 0.0f) && (fy[c] <= (float)(H-1));
            if (valid) {
                int ix = (int)fx[c];
                int iy = (int)fy[c];
                float4 t = apack[(b << 18) + iy * W + ix];
                float wgt = wt[c];
                a0 += wgt * t.x; a1 += wgt * t.y; a2 += wgt * t.z;
            }
        }
    }

    int obase = b * 3 * HW + hw;
    out[OFF_IMAGES + obase         ] = a0 * s0 * vis;
    out[OFF_IMAGES + obase +   HW  ] = a1 * s1 * vis;
    out[OFF_IMAGES + obase + 2*HW  ] = a2 * s2 * vis;
    out[OFF_ALBEDO + obase         ] = a0;
    out[OFF_ALBEDO + obase +   HW  ] = a1;
    out[OFF_ALBEDO + obase + 2*HW  ] = a2;
    out[OFF_ALPHA   + pix] = vis;
    out[OFF_POSMASK + pix] = (tz < -0.05f) ? 1.0f : 0.0f;
    out[OFF_SHADING + obase        ] = s0;
    out[OFF_SHADING + obase +   HW ] = s1;
    out[OFF_SHADING + obase + 2*HW ] = s2;
    *reinterpret_cast<float2*>(out + OFF_GRID + (size_t)pix*2) = make_float2(u, v);
}

} // namespace

extern "C" void kernel_launch(void* const* d_in, const int* in_sizes, int n_in,
                              void* d_out, int out_size, void* d_ws, size_t ws_size,
                              hipStream_t stream) {
    const float* verts  = (const float*)d_in[0];
    const float* tverts = (const float*)d_in[1];
    const float* albedo = (const float*)d_in[2];
    const float* lights = (const float*)d_in[3];
    const float* fuv    = (const float*)d_in[4];
    const float* bary   = (const float*)d_in[5];
    const int*   faces  = (const int*)d_in[6];
    const int*   ptf    = (const int*)d_in[7];
    float* out = (float*)d_out;

    char* ws = (char*)d_ws;
    int* counts  = (int*)ws;                              // V
    int* offsets = counts + V;                            // V+1
    int* cursor  = offsets + V + 1;                       // V
    int* keys    = cursor + V;                            // 3*NF
    float* normT = (float*)(keys + 3*NF);                 // B*V*3
    char* pend   = (char*)(normT + (size_t)B*V*3);
    size_t ftab_off  = (((size_t)(pend - ws)) + 255) & ~(size_t)255;
    size_t apack_off = (ftab_off + (size_t)B*NF*6*sizeof(float4) + 255) & ~(size_t)255;
    float4* ftab  = (float4*)(ws + ftab_off);             // 3.84 MB
    float4* apack = (float4*)(ws + apack_off);            // 16.78 MB
    float* normV = out + OFF_NORMALS;

    hipMemsetAsync(counts, 0, (size_t)V * sizeof(int), stream);
    count_k<<<(NF + 255)/256, 256, 0, stream>>>(faces, counts);
    scan_k<<<1, 1024, 0, stream>>>(counts, offsets, cursor);
    fill_k<<<(NF + 255)/256, 256, 0, stream>>>(faces, cursor, keys);
    sort_k<<<(V + 255)/256, 256, 0, stream>>>(offsets, keys);
    accum_k<<<(B*V + 255)/256, 256, 0, stream>>>(offsets, keys, faces, verts, tverts,
                                                 normV, normT);
    int pack_blocks = NPIX/256 + (B*NF + 255)/256;
    pack_k<<<pack_blocks, 256, 0, stream>>>(faces, fuv, normV, normT, albedo, ftab, apack);
    pixel_k<<<NPIX/256, 256, 0, stream>>>(ptf, bary, apack, lights, ftab, out);
}